// Round 4
// baseline (289.183 us; speedup 1.0000x reference)
//
#include <hip/hip_runtime.h>
#include <cstddef>

#define A_ATOMS 96
#define BATCH   128
#define NNODES  12288   // B*A
#define NB      8       // nodes per block (node_k)
#define AS      132     // AsL / workS stride (132%32=4)
#define XS      196     // xinS stride (196%32=4)

typedef float v2f __attribute__((ext_vector_type(2)));

__device__ __forceinline__ float silu_f(float x) {
    float e = __expf(-x);
    return x * __builtin_amdgcn_rcpf(1.0f + e);
}
__device__ __forceinline__ v2f silu2(v2f x) {
    v2f r; r.x = silu_f(x.x); r.y = silu_f(x.y); return r;
}

#define RED64(v) { v += __shfl_xor(v, 1); v += __shfl_xor(v, 2); v += __shfl_xor(v, 4); \
                   v += __shfl_xor(v, 8); v += __shfl_xor(v, 16); v += __shfl_xor(v, 32); }
#define RED16(v) { v += __shfl_xor(v, 1); v += __shfl_xor(v, 2); v += __shfl_xor(v, 4); \
                   v += __shfl_xor(v, 8); }

// ===== fused node kernel v4: 128 threads, 2 nodes/thread (unchanged R2) =====
__global__ __launch_bounds__(128, 3)
void node_k(const float* __restrict__ vrep, const float* __restrict__ mixW1,
            const float* __restrict__ srep,
            const float* __restrict__ sc1W1, const float* __restrict__ sc1b1,
            const float* __restrict__ sc1W2, const float* __restrict__ sc1b2,
            const float* __restrict__ mixW2,
            const float* __restrict__ sc2W1, const float* __restrict__ sc2b1,
            const float* __restrict__ sc2W2, const float* __restrict__ sc2b2,
            float* __restrict__ l0v, float* __restrict__ l1v) {
    __shared__ float AsL[24 * AS];
    __shared__ float xinS[NB * XS];
    __shared__ float s1s[2][4][64];
    __shared__ float pwp[NB][6];

    const int t  = threadIdx.x;
    const int w  = t >> 6;
    const int ln = t & 63;
    const int cx = ln & 15;
    const int ry = ln >> 4;
    const int cb = w * 64 + cx * 4;
    const int row0  = blockIdx.x * 24;
    const int node0 = blockIdx.x * NB;

#pragma unroll
    for (int it = 0; it < 6; it++) {
        const int idx = it * 128 + t;
        const int r   = idx >> 5;
        const int c4  = (idx & 31) * 4;
        *(float4*)&AsL[r * AS + c4] = *(const float4*)(vrep + (size_t)(row0 + r) * 128 + c4);
    }
#pragma unroll
    for (int it = 0; it < 2; it++) {
        const int idx = it * 128 + t;
        const int a   = idx >> 5;
        const int c4  = (idx & 31) * 4;
        *(float4*)&xinS[a * XS + c4] = *(const float4*)(srep + (size_t)(node0 + a) * 128 + c4);
    }
    __syncthreads();

    float acc[2][3][4];
#pragma unroll
    for (int p = 0; p < 2; p++)
#pragma unroll
        for (int d = 0; d < 3; d++)
#pragma unroll
            for (int j = 0; j < 4; j++) acc[p][d][j] = 0.0f;

    for (int kc = 0; kc < 128; kc += 8) {
        float a[2][3][8];
#pragma unroll
        for (int p = 0; p < 2; p++)
#pragma unroll
            for (int d = 0; d < 3; d++) {
                const int row = (3 * (ry + 4 * p) + d) * AS + kc;
                *(float4*)&a[p][d][0] = *(const float4*)&AsL[row];
                *(float4*)&a[p][d][4] = *(const float4*)&AsL[row + 4];
            }
#pragma unroll
        for (int kk = 0; kk < 8; kk++) {
            float b[4];
            *(float4*)b = *(const float4*)(mixW1 + (size_t)(kc + kk) * 128 + cb);
#pragma unroll
            for (int p = 0; p < 2; p++)
#pragma unroll
                for (int d = 0; d < 3; d++)
#pragma unroll
                    for (int j = 0; j < 4; j++)
                        acc[p][d][j] += a[p][d][kk] * b[j];
        }
    }
    if (w == 0) {
#pragma unroll
        for (int p = 0; p < 2; p++) {
            float nrm[4];
#pragma unroll
            for (int c = 0; c < 4; c++)
                nrm[c] = sqrtf(acc[p][0][c] * acc[p][0][c] + acc[p][1][c] * acc[p][1][c]
                             + acc[p][2][c] * acc[p][2][c]);
            *(float4*)&xinS[(ry + 4 * p) * XS + 128 + cb] = *(float4*)nrm;
        }
    }
    __syncthreads();

    float* workS = AsL;
    {
        float acc3[2][4];
#pragma unroll
        for (int p = 0; p < 2; p++)
#pragma unroll
            for (int j = 0; j < 4; j++) acc3[p][j] = 0.0f;
        for (int kc = 0; kc < 192; kc += 8) {
            float af[2][8];
#pragma unroll
            for (int p = 0; p < 2; p++) {
                const int row = (ry + 4 * p) * XS + kc;
                *(float4*)&af[p][0] = *(const float4*)&xinS[row];
                *(float4*)&af[p][4] = *(const float4*)&xinS[row + 4];
            }
#pragma unroll
            for (int kk = 0; kk < 8; kk++) {
                float b[4];
                *(float4*)b = *(const float4*)(sc1W1 + (size_t)(kc + kk) * 128 + cb);
#pragma unroll
                for (int p = 0; p < 2; p++)
#pragma unroll
                    for (int j = 0; j < 4; j++) acc3[p][j] += af[p][kk] * b[j];
            }
        }
#pragma unroll
        for (int p = 0; p < 2; p++) {
            float h[4];
#pragma unroll
            for (int j = 0; j < 4; j++) h[j] = silu_f(acc3[p][j] + sc1b1[cb + j]);
            *(float4*)&workS[(ry + 4 * p) * AS + cb] = *(float4*)h;
        }
    }
    __syncthreads();

    float xg[2][4];
    {
        float acc4[2][4];
#pragma unroll
        for (int p = 0; p < 2; p++)
#pragma unroll
            for (int j = 0; j < 4; j++) acc4[p][j] = 0.0f;
        for (int kc = 0; kc < 128; kc += 8) {
            float af[2][8];
#pragma unroll
            for (int p = 0; p < 2; p++) {
                const int row = (ry + 4 * p) * AS + kc;
                *(float4*)&af[p][0] = *(const float4*)&workS[row];
                *(float4*)&af[p][4] = *(const float4*)&workS[row + 4];
            }
#pragma unroll
            for (int kk = 0; kk < 8; kk++) {
                float b[4];
                *(float4*)b = *(const float4*)(sc1W2 + (size_t)(kc + kk) * 128 + cb);
#pragma unroll
                for (int p = 0; p < 2; p++)
#pragma unroll
                    for (int j = 0; j < 4; j++) acc4[p][j] += af[p][kk] * b[j];
            }
        }
        if (w == 0) {
#pragma unroll
            for (int p = 0; p < 2; p++) {
                float xs[4];
#pragma unroll
                for (int j = 0; j < 4; j++) xs[j] = acc4[p][j] + sc1b2[cb + j];
                *(float4*)&xinS[(ry + 4 * p) * XS + cb] = *(float4*)xs;
            }
        } else {
#pragma unroll
            for (int p = 0; p < 2; p++)
#pragma unroll
                for (int j = 0; j < 4; j++) xg[p][j] = acc4[p][j] + sc1b2[cb + j];
        }
    }

    if (w == 1) {
#pragma unroll
        for (int p = 0; p < 2; p++) {
            float p0 = 0, p1 = 0, p2 = 0, p3 = 0, p4 = 0, p5 = 0;
#pragma unroll
            for (int c = 0; c < 4; c++) {
                float2 m = *(const float2*)(mixW2 + (size_t)(cb - 64 + c) * 2);
                const float v0 = xg[p][c] * acc[p][0][c];
                const float v1 = xg[p][c] * acc[p][1][c];
                const float v2 = xg[p][c] * acc[p][2][c];
                p0 += v0 * m.x; p1 += v0 * m.y;
                p2 += v1 * m.x; p3 += v1 * m.y;
                p4 += v2 * m.x; p5 += v2 * m.y;
            }
            RED16(p0); RED16(p1); RED16(p2); RED16(p3); RED16(p4); RED16(p5);
            if (cx == 0) {
                const int nl = ry + 4 * p;
                pwp[nl][0] = p0; pwp[nl][1] = p1;
                pwp[nl][2] = p2; pwp[nl][3] = p3;
                pwp[nl][4] = p4; pwp[nl][5] = p5;
            }
        }
    }
    __syncthreads();

    {
        const float bb1 = sc2b1[ln];
        const float wn  = sc2W1[64 * 64 + ln];
        const float wq0 = sc2W2[ln * 2 + 0], wq1 = sc2W2[ln * 2 + 1];
        float vn2[4], g0[4], g1[4], g2[4];
#pragma unroll
        for (int r = 0; r < 4; r++) {
            const int nl = r * 2 + w;
            const float q00 = pwp[nl][0], q10 = pwp[nl][2], q20 = pwp[nl][4];
            vn2[r] = sqrtf(q00 * q00 + q10 * q10 + q20 * q20);
            g0[r] = pwp[nl][1]; g1[r] = pwp[nl][3]; g2[r] = pwp[nl][5];
            s1s[w][r][ln] = silu_f(xinS[nl * XS + ln]);
        }
        __builtin_amdgcn_s_waitcnt(0);
        float acc5[4];
#pragma unroll
        for (int r = 0; r < 4; r++) acc5[r] = bb1 + vn2[r] * wn;
#pragma unroll 8
        for (int i2 = 0; i2 < 64; i2++) {
            const float wv = sc2W1[i2 * 64 + ln];
#pragma unroll
            for (int r = 0; r < 4; r++) acc5[r] += s1s[w][r][i2] * wv;
        }
#pragma unroll
        for (int r = 0; r < 4; r++) {
            const float h2 = silu_f(acc5[r]);
            float q0 = h2 * wq0, q1 = h2 * wq1;
            RED64(q0); RED64(q1);
            if (ln == 0) {
                const int n = node0 + r * 2 + w;
                const float gate = q1 + sc2b2[1];
                l0v[n] = q0 + sc2b2[0];
                l1v[(size_t)n * 3 + 0] = gate * g0[r];
                l1v[(size_t)n * 3 + 1] = gate * g1[r];
                l1v[(size_t)n * 3 + 2] = gate * g2[r];
            }
        }
    }
}

// ---------- pairpre v3: h-blocked-by-4 layout for float4 loads in pair_k ----
// P layout (floats, N = NNODES):
//   Pv4 [a<3][hb<7][j][4]  at 0        (h = hb*4+hr, h<28)
//   Pv2 [a<3][j][2]        at 84N      (h = 28+hr)
//   Pr4                    at 90N
//   Pr2                    at 174N
//   Ps4 [hb<7][j][4]       at 180N
//   Ps2 [j][2]             at 208N     (total 210N, same as before)
__global__ __launch_bounds__(256)
void pairpre_k(const float* __restrict__ l1v, const float* __restrict__ pos,
               const float* __restrict__ l0v,
               const float* __restrict__ vvW1, const float* __restrict__ vrW1,
               const float* __restrict__ sW1, const float* __restrict__ sb1,
               float* __restrict__ P) {
    const int jl = threadIdx.x & 31;
    const int sq = threadIdx.x >> 5;        // 0..7
    const int j  = blockIdx.x * 32 + jl;
    const float lj0 = l1v[j * 3 + 0], lj1 = l1v[j * 3 + 1], lj2 = l1v[j * 3 + 2];
    const float pj0 = pos[j * 3 + 0], pj1 = pos[j * 3 + 1], pj2 = pos[j * 3 + 2];
    const float l0j = l0v[j];
    float* Pv4 = P;
    float* Pv2 = P + (size_t)84 * NNODES;
    float* Pr4 = P + (size_t)90 * NNODES;
    float* Pr2 = P + (size_t)174 * NNODES;
    float* Ps4 = P + (size_t)180 * NNODES;
    float* Ps2 = P + (size_t)208 * NNODES;

#pragma unroll
    for (int it = 0; it < 7; it++) {
        const int task = it * 8 + sq;       // 0..55
        if (task < 21) {                    // Pv4
            const int a  = (task >= 14) ? 2 : ((task >= 7) ? 1 : 0);
            const int hb = task - a * 7;
            float v[4];
#pragma unroll
            for (int hr = 0; hr < 4; hr++) {
                const int h = hb * 4 + hr;
                v[hr] = lj0 * vvW1[(3 * a + 0) * 30 + h] + lj1 * vvW1[(3 * a + 1) * 30 + h]
                      + lj2 * vvW1[(3 * a + 2) * 30 + h];
            }
            *(float4*)&Pv4[(((size_t)(a * 7 + hb)) * NNODES + j) * 4] = *(float4*)v;
        } else if (task < 42) {             // Pr4
            const int tt = task - 21;
            const int a  = (tt >= 14) ? 2 : ((tt >= 7) ? 1 : 0);
            const int hb = tt - a * 7;
            float r[4];
#pragma unroll
            for (int hr = 0; hr < 4; hr++) {
                const int h = hb * 4 + hr;
                r[hr] = pj0 * vrW1[(3 * a + 0) * 30 + h] + pj1 * vrW1[(3 * a + 1) * 30 + h]
                      + pj2 * vrW1[(3 * a + 2) * 30 + h];
            }
            *(float4*)&Pr4[(((size_t)(a * 7 + hb)) * NNODES + j) * 4] = *(float4*)r;
        } else if (task < 49) {             // Ps4
            const int hb = task - 42;
            float s[4];
#pragma unroll
            for (int hr = 0; hr < 4; hr++) {
                const int h = hb * 4 + hr;
                s[hr] = sb1[h] + l0j * sW1[30 + h];
            }
            *(float4*)&Ps4[((size_t)hb * NNODES + j) * 4] = *(float4*)s;
        } else if (task < 52) {             // Pv2 tail (h=28,29)
            const int a = task - 49;
            float v[2];
#pragma unroll
            for (int hr = 0; hr < 2; hr++) {
                const int h = 28 + hr;
                v[hr] = lj0 * vvW1[(3 * a + 0) * 30 + h] + lj1 * vvW1[(3 * a + 1) * 30 + h]
                      + lj2 * vvW1[(3 * a + 2) * 30 + h];
            }
            *(float2*)&Pv2[((size_t)a * NNODES + j) * 2] = *(float2*)v;
        } else if (task < 55) {             // Pr2 tail
            const int a = task - 52;
            float r[2];
#pragma unroll
            for (int hr = 0; hr < 2; hr++) {
                const int h = 28 + hr;
                r[hr] = pj0 * vrW1[(3 * a + 0) * 30 + h] + pj1 * vrW1[(3 * a + 1) * 30 + h]
                      + pj2 * vrW1[(3 * a + 2) * 30 + h];
            }
            *(float2*)&Pr2[((size_t)a * NNODES + j) * 2] = *(float2*)r;
        } else {                            // Ps2 tail
            float s[2];
#pragma unroll
            for (int hr = 0; hr < 2; hr++) {
                const int h = 28 + hr;
                s[hr] = sb1[h] + l0j * sW1[30 + h];
            }
            *(float2*)&Ps2[(size_t)j * 2] = *(float2*)s;
        }
    }
}

// ---------- pair kernel v5: float4 P-loads + register double-buffer --------
// Grid (A/8, B), 192 threads; 4 i-atoms/thread (2 v2f sets). Per 4-h group:
// 7 coalesced float4 loads, issued one group ahead of use (~500 issue-cyc of
// math per group >> ~250 cyc L2 latency) -> no exposed vmcnt stalls.
__global__ __launch_bounds__(192)
void pair_k(const float* __restrict__ l0v, const float* __restrict__ l1v,
            const float* __restrict__ P,
            const float* __restrict__ vvb1, const float* __restrict__ vrb1,
            const float* __restrict__ sW1,
            const float* __restrict__ vvW2, const float* __restrict__ vrW2,
            const float* __restrict__ sW2,
            const float* __restrict__ vvb2, const float* __restrict__ vrb2,
            const float* __restrict__ sb2,
            const float* __restrict__ hW1,  const float* __restrict__ hb1,
            const float* __restrict__ hW2,  const float* __restrict__ hb2,
            float* __restrict__ out) {
    const int t = threadIdx.x;
    const int b = blockIdx.y;
    const int g = (t >= 96) ? 1 : 0;
    const int j = t - g * 96;
    const int i0 = blockIdx.x * 8 + g * 4;
    const int ni0 = b * A_ATOMS + i0;       // set A: ni0, ni0+1
    const int ni2 = ni0 + 2;                // set B: ni2, ni2+1
    const int nj  = b * A_ATOMS + j;

    const float* Pv4 = P;
    const float* Pv2 = P + (size_t)84 * NNODES;
    const float* Pr4 = P + (size_t)90 * NNODES;
    const float* Pr2 = P + (size_t)174 * NNODES;
    const float* Ps4 = P + (size_t)180 * NNODES;
    const float* Ps2 = P + (size_t)208 * NNODES;

    const v2f liA0 = { l1v[ni0 * 3 + 0], l1v[(ni0 + 1) * 3 + 0] };
    const v2f liA1 = { l1v[ni0 * 3 + 1], l1v[(ni0 + 1) * 3 + 1] };
    const v2f liA2 = { l1v[ni0 * 3 + 2], l1v[(ni0 + 1) * 3 + 2] };
    const v2f s0iA = { l0v[ni0], l0v[ni0 + 1] };
    const v2f liB0 = { l1v[ni2 * 3 + 0], l1v[(ni2 + 1) * 3 + 0] };
    const v2f liB1 = { l1v[ni2 * 3 + 1], l1v[(ni2 + 1) * 3 + 1] };
    const v2f liB2 = { l1v[ni2 * 3 + 2], l1v[(ni2 + 1) * 3 + 2] };
    const v2f s0iB = { l0v[ni2], l0v[ni2 + 1] };

    v2f tA[9], tB[9];
#pragma unroll
    for (int l = 0; l < 9; l++) {
        const float t0 = vvb2[l] + vrb2[l] + sb2[l];
        tA[l] = (v2f)t0; tB[l] = (v2f)t0;
    }

#define LD4V(a, hb) (*(const float4*)&Pv4[(((size_t)((a) * 7 + (hb))) * NNODES + nj) * 4])
#define LD4R(a, hb) (*(const float4*)&Pr4[(((size_t)((a) * 7 + (hb))) * NNODES + nj) * 4])
#define LD4S(hb)    (*(const float4*)&Ps4[((size_t)(hb) * NNODES + nj) * 4])

#define PAIR_H_BODY(H, PV0, PV1, PV2_, PR0, PR1, PR2_, PS)                    \
    {                                                                         \
        const float sw = sW1[(H)];                                            \
        const float bv = vvb1[(H)], br = vrb1[(H)];                           \
        v2f avA = (v2f)(bv) + liA0 * (PV0) + liA1 * (PV1) + liA2 * (PV2_);    \
        v2f arA = (v2f)(br) + liA0 * (PR0) + liA1 * (PR1) + liA2 * (PR2_);    \
        v2f asA = (v2f)(PS) + s0iA * sw;                                      \
        v2f avB = (v2f)(bv) + liB0 * (PV0) + liB1 * (PV1) + liB2 * (PV2_);    \
        v2f arB = (v2f)(br) + liB0 * (PR0) + liB1 * (PR1) + liB2 * (PR2_);    \
        v2f asB = (v2f)(PS) + s0iB * sw;                                      \
        avA = silu2(avA); arA = silu2(arA); asA = silu2(asA);                 \
        avB = silu2(avB); arB = silu2(arB); asB = silu2(asB);                 \
        _Pragma("unroll")                                                     \
        for (int l = 0; l < 9; l++) {                                         \
            const float w2v = vvW2[(H) * 9 + l];                              \
            const float w2r = vrW2[(H) * 9 + l];                              \
            const float w2s = sW2[(H) * 9 + l];                               \
            tA[l] += avA * w2v + arA * w2r + asA * w2s;                       \
            tB[l] += avB * w2v + arB * w2r + asB * w2s;                       \
        }                                                                     \
    }

    // tail loads hoisted to the front (live across the whole loop1)
    const float2 tv0 = *(const float2*)&Pv2[((size_t)0 * NNODES + nj) * 2];
    const float2 tv1 = *(const float2*)&Pv2[((size_t)1 * NNODES + nj) * 2];
    const float2 tv2 = *(const float2*)&Pv2[((size_t)2 * NNODES + nj) * 2];
    const float2 tr0 = *(const float2*)&Pr2[((size_t)0 * NNODES + nj) * 2];
    const float2 tr1 = *(const float2*)&Pr2[((size_t)1 * NNODES + nj) * 2];
    const float2 tr2 = *(const float2*)&Pr2[((size_t)2 * NNODES + nj) * 2];
    const float2 ts2 = *(const float2*)&Ps2[(size_t)nj * 2];

    // prefetch group 0
    float4 cv0 = LD4V(0, 0), cv1 = LD4V(1, 0), cv2 = LD4V(2, 0);
    float4 cr0 = LD4R(0, 0), cr1 = LD4R(1, 0), cr2 = LD4R(2, 0);
    float4 cs  = LD4S(0);

    for (int hb = 0; hb < 7; hb++) {
        float4 nv0, nv1, nv2, nr0, nr1, nr2, ns;
        if (hb < 6) {
            nv0 = LD4V(0, hb + 1); nv1 = LD4V(1, hb + 1); nv2 = LD4V(2, hb + 1);
            nr0 = LD4R(0, hb + 1); nr1 = LD4R(1, hb + 1); nr2 = LD4R(2, hb + 1);
            ns  = LD4S(hb + 1);
        }
#pragma unroll
        for (int hr = 0; hr < 4; hr++) {
            const int h = hb * 4 + hr;
            PAIR_H_BODY(h, (&cv0.x)[hr], (&cv1.x)[hr], (&cv2.x)[hr],
                           (&cr0.x)[hr], (&cr1.x)[hr], (&cr2.x)[hr],
                           (&cs.x)[hr]);
        }
        if (hb < 6) {
            cv0 = nv0; cv1 = nv1; cv2 = nv2;
            cr0 = nr0; cr1 = nr1; cr2 = nr2;
            cs  = ns;
        }
    }
    // tail h = 28, 29
#pragma unroll
    for (int hr = 0; hr < 2; hr++) {
        const int h = 28 + hr;
        PAIR_H_BODY(h, (&tv0.x)[hr], (&tv1.x)[hr], (&tv2.x)[hr],
                       (&tr0.x)[hr], (&tr1.x)[hr], (&tr2.x)[hr],
                       (&ts2.x)[hr]);
    }

    v2f oA[9], oB[9];
#pragma unroll
    for (int l = 0; l < 9; l++) {
        oA[l] = (v2f)(hb2[l]); oB[l] = (v2f)(hb2[l]);
    }
#pragma unroll 2
    for (int h = 0; h < 30; h++) {
        v2f aA = (v2f)(hb1[h]), aB = (v2f)(hb1[h]);
#pragma unroll
        for (int m = 0; m < 9; m++) {
            const float w1 = hW1[m * 30 + h];
            aA += tA[m] * w1; aB += tB[m] * w1;
        }
        aA = silu2(aA); aB = silu2(aB);
#pragma unroll
        for (int l = 0; l < 9; l++) {
            const float w2 = hW2[h * 9 + l];
            oA[l] += aA * w2; oB[l] += aB * w2;
        }
    }

    // out[((b*A+i)*3+k)*288 + j*3 + l]
#pragma unroll
    for (int k = 0; k < 3; k++) {
        const size_t offA0 = ((size_t)ni0 * 3 + k) * 288 + (size_t)j * 3;
        const size_t offA1 = offA0 + 3 * 288;
        out[offA0 + 0] = oA[3 * k + 0].x;
        out[offA0 + 1] = oA[3 * k + 1].x;
        out[offA0 + 2] = oA[3 * k + 2].x;
        out[offA1 + 0] = oA[3 * k + 0].y;
        out[offA1 + 1] = oA[3 * k + 1].y;
        out[offA1 + 2] = oA[3 * k + 2].y;
        const size_t offB0 = ((size_t)ni2 * 3 + k) * 288 + (size_t)j * 3;
        const size_t offB1 = offB0 + 3 * 288;
        out[offB0 + 0] = oB[3 * k + 0].x;
        out[offB0 + 1] = oB[3 * k + 1].x;
        out[offB0 + 2] = oB[3 * k + 2].x;
        out[offB1 + 0] = oB[3 * k + 0].y;
        out[offB1 + 1] = oB[3 * k + 1].y;
        out[offB1 + 2] = oB[3 * k + 2].y;
    }
}

extern "C" void kernel_launch(void* const* d_in, const int* in_sizes, int n_in,
                              void* d_out, int out_size, void* d_ws, size_t ws_size,
                              hipStream_t stream) {
    const float* pos   = (const float*)d_in[0];
    const float* srep  = (const float*)d_in[1];
    const float* vrep  = (const float*)d_in[2];
    const float* mixW1 = (const float*)d_in[3];
    const float* sc1W1 = (const float*)d_in[4];
    const float* sc1b1 = (const float*)d_in[5];
    const float* sc1W2 = (const float*)d_in[6];
    const float* sc1b2 = (const float*)d_in[7];
    const float* mixW2 = (const float*)d_in[8];
    const float* sc2W1 = (const float*)d_in[9];
    const float* sc2b1 = (const float*)d_in[10];
    const float* sc2W2 = (const float*)d_in[11];
    const float* sc2b2 = (const float*)d_in[12];
    const float* vvW1  = (const float*)d_in[13];
    const float* vvb1  = (const float*)d_in[14];
    const float* vvW2  = (const float*)d_in[15];
    const float* vvb2  = (const float*)d_in[16];
    const float* vrW1  = (const float*)d_in[17];
    const float* vrb1  = (const float*)d_in[18];
    const float* vrW2  = (const float*)d_in[19];
    const float* vrb2  = (const float*)d_in[20];
    const float* sW1   = (const float*)d_in[21];
    const float* sb1   = (const float*)d_in[22];
    const float* sW2   = (const float*)d_in[23];
    const float* sb2   = (const float*)d_in[24];
    const float* hW1   = (const float*)d_in[25];
    const float* hb1   = (const float*)d_in[26];
    const float* hW2   = (const float*)d_in[27];
    const float* hb2   = (const float*)d_in[28];

    float* ws  = (float*)d_ws;
    float* P   = ws;                               // 210*NNODES floats
    float* l0v = ws + (size_t)210 * NNODES;        // 12,288
    float* l1v = l0v + NNODES;                     // 36,864
    float* outf = (float*)d_out;

    // 1. fused node stage -> l0, l1
    node_k<<<NNODES / NB, 128, 0, stream>>>(
        vrep, mixW1, srep,
        sc1W1, sc1b1, sc1W2, sc1b2,
        mixW2, sc2W1, sc2b1, sc2W2, sc2b2,
        l0v, l1v);

    // 2. P-tables (h-blocked float4 layout)
    pairpre_k<<<NNODES / 32, 256, 0, stream>>>(l1v, pos, l0v, vvW1, vrW1,
                                               sW1, sb1, P);

    // 3. pair stage (4 i per thread, float4 P-loads, double-buffered)
    pair_k<<<dim3(A_ATOMS / 8, BATCH), 192, 0, stream>>>(
        l0v, l1v, P,
        vvb1, vrb1, sW1,
        vvW2, vrW2, sW2,
        vvb2, vrb2, sb2,
        hW1, hb1, hW2, hb2,
        outf);
}

// Round 6
// 270.238 us; speedup vs baseline: 1.0701x; 1.0701x over previous
//
#include <hip/hip_runtime.h>
#include <cstddef>

#define A_ATOMS 96
#define BATCH   128
#define NNODES  12288   // B*A
#define NB      8       // nodes per block (node_k)
#define AS      132     // AsL / workS stride (132%32=4)
#define XS      196     // xinS stride (196%32=4)

typedef float v2f __attribute__((ext_vector_type(2)));

__device__ __forceinline__ float silu_f(float x) {
    float e = __expf(-x);
    return x * __builtin_amdgcn_rcpf(1.0f + e);
}
__device__ __forceinline__ v2f silu2(v2f x) {
    v2f r; r.x = silu_f(x.x); r.y = silu_f(x.y); return r;
}

#define RED64(v) { v += __shfl_xor(v, 1); v += __shfl_xor(v, 2); v += __shfl_xor(v, 4); \
                   v += __shfl_xor(v, 8); v += __shfl_xor(v, 16); v += __shfl_xor(v, 32); }
#define RED16(v) { v += __shfl_xor(v, 1); v += __shfl_xor(v, 2); v += __shfl_xor(v, 4); \
                   v += __shfl_xor(v, 8); }

// ===== fused node kernel v5: ping-pong weight prefetch + P-emit tail ========
// 128 threads, 2 nodes/thread. Weight loads for k-step group G+1 issue before
// the FMAs of group G (384 issue-cyc of FMA per 8-k group >> ~300cyc L2 lat).
// VGPR cost of prefetch is free: occupancy is LDS/grid-bound at 6 blocks/CU.
// Tail: emits the 210 P-rows for this block's 8 nodes (pairpre_k eliminated).
__global__ __launch_bounds__(128, 3)
void node_k(const float* __restrict__ vrep, const float* __restrict__ mixW1,
            const float* __restrict__ srep,
            const float* __restrict__ sc1W1, const float* __restrict__ sc1b1,
            const float* __restrict__ sc1W2, const float* __restrict__ sc1b2,
            const float* __restrict__ mixW2,
            const float* __restrict__ sc2W1, const float* __restrict__ sc2b1,
            const float* __restrict__ sc2W2, const float* __restrict__ sc2b2,
            const float* __restrict__ pos,
            const float* __restrict__ vvW1, const float* __restrict__ vrW1,
            const float* __restrict__ sW1,  const float* __restrict__ sb1,
            float* __restrict__ l0v, float* __restrict__ l1v,
            float* __restrict__ P) {
    __shared__ float AsL[24 * AS];
    __shared__ float xinS[NB * XS];
    __shared__ float s1s[2][4][64];
    __shared__ float pwp[NB][6];
    __shared__ float gateS[NB], l0S[NB];

    const int t  = threadIdx.x;
    const int w  = t >> 6;
    const int ln = t & 63;
    const int cx = ln & 15;
    const int ry = ln >> 4;
    const int cb = w * 64 + cx * 4;
    const int row0  = blockIdx.x * 24;
    const int node0 = blockIdx.x * NB;

#pragma unroll
    for (int it = 0; it < 6; it++) {
        const int idx = it * 128 + t;
        const int r   = idx >> 5;
        const int c4  = (idx & 31) * 4;
        *(float4*)&AsL[r * AS + c4] = *(const float4*)(vrep + (size_t)(row0 + r) * 128 + c4);
    }
#pragma unroll
    for (int it = 0; it < 2; it++) {
        const int idx = it * 128 + t;
        const int a   = idx >> 5;
        const int c4  = (idx & 31) * 4;
        *(float4*)&xinS[a * XS + c4] = *(const float4*)(srep + (size_t)(node0 + a) * 128 + c4);
    }
    __syncthreads();

    // ---- mix1: vmix[2 nodes][3 dims][4 cols], prefetched weights ------------
    float acc[2][3][4];
#pragma unroll
    for (int p = 0; p < 2; p++)
#pragma unroll
        for (int d = 0; d < 3; d++)
#pragma unroll
            for (int j = 0; j < 4; j++) acc[p][d][j] = 0.0f;

#define LOADW8(dst, Wmat, kc0)                                                \
    _Pragma("unroll")                                                         \
    for (int kk = 0; kk < 8; kk++)                                            \
        dst[kk] = *(const float4*)((Wmat) + (size_t)((kc0) + kk) * 128 + cb);

#define MIX1_HALF(wbuf, kc0)                                                  \
    _Pragma("unroll")                                                         \
    for (int p = 0; p < 2; p++) {                                             \
        float a_[3][8];                                                       \
        _Pragma("unroll")                                                     \
        for (int d = 0; d < 3; d++) {                                         \
            const int rr = (3 * (ry + 4 * p) + d) * AS + (kc0);               \
            *(float4*)&a_[d][0] = *(const float4*)&AsL[rr];                   \
            *(float4*)&a_[d][4] = *(const float4*)&AsL[rr + 4];               \
        }                                                                     \
        _Pragma("unroll")                                                     \
        for (int kk = 0; kk < 8; kk++)                                        \
            _Pragma("unroll")                                                 \
            for (int d = 0; d < 3; d++)                                       \
                _Pragma("unroll")                                             \
                for (int j = 0; j < 4; j++)                                   \
                    acc[p][d][j] += a_[d][kk] * (&wbuf[kk].x)[j];             \
    }

    {
        float4 wA[8], wB[8];
        LOADW8(wA, mixW1, 0);
        for (int kc = 0; kc < 128; kc += 16) {
            LOADW8(wB, mixW1, kc + 8);
            MIX1_HALF(wA, kc);
            if (kc + 16 < 128) { LOADW8(wA, mixW1, kc + 16); }
            MIX1_HALF(wB, kc + 8);
        }
    }
    if (w == 0) {
#pragma unroll
        for (int p = 0; p < 2; p++) {
            float nrm[4];
#pragma unroll
            for (int c = 0; c < 4; c++)
                nrm[c] = sqrtf(acc[p][0][c] * acc[p][0][c] + acc[p][1][c] * acc[p][1][c]
                             + acc[p][2][c] * acc[p][2][c]);
            *(float4*)&xinS[(ry + 4 * p) * XS + 128 + cb] = *(float4*)nrm;
        }
    }
    __syncthreads();

    // ---- sc1 layer 1: xin(192) @ sc1W1(192x128) -> silu, prefetched ---------
    float* workS = AsL;
    {
        float acc3[2][4];
#pragma unroll
        for (int p = 0; p < 2; p++)
#pragma unroll
            for (int j = 0; j < 4; j++) acc3[p][j] = 0.0f;

#define SC1_HALF(accv, Sbuf, SST, wbuf, kc0)                                  \
    _Pragma("unroll")                                                         \
    for (int p = 0; p < 2; p++) {                                             \
        float af[8];                                                          \
        const int rr = (ry + 4 * p) * (SST) + (kc0);                          \
        *(float4*)&af[0] = *(const float4*)&Sbuf[rr];                         \
        *(float4*)&af[4] = *(const float4*)&Sbuf[rr + 4];                     \
        _Pragma("unroll")                                                     \
        for (int kk = 0; kk < 8; kk++)                                        \
            _Pragma("unroll")                                                 \
            for (int j = 0; j < 4; j++)                                       \
                accv[p][j] += af[kk] * (&wbuf[kk].x)[j];                      \
    }

        float4 wA[8], wB[8];
        LOADW8(wA, sc1W1, 0);
        for (int kc = 0; kc < 192; kc += 16) {
            LOADW8(wB, sc1W1, kc + 8);
            SC1_HALF(acc3, xinS, XS, wA, kc);
            if (kc + 16 < 192) { LOADW8(wA, sc1W1, kc + 16); }
            SC1_HALF(acc3, xinS, XS, wB, kc + 8);
        }
#pragma unroll
        for (int p = 0; p < 2; p++) {
            float h[4];
#pragma unroll
            for (int j = 0; j < 4; j++) h[j] = silu_f(acc3[p][j] + sc1b1[cb + j]);
            *(float4*)&workS[(ry + 4 * p) * AS + cb] = *(float4*)h;
        }
    }
    __syncthreads();

    // ---- sc1 layer 2: h(128) @ sc1W2(128x128), prefetched -------------------
    float xg[2][4];
    {
        float acc4[2][4];
#pragma unroll
        for (int p = 0; p < 2; p++)
#pragma unroll
            for (int j = 0; j < 4; j++) acc4[p][j] = 0.0f;

        float4 wA[8], wB[8];
        LOADW8(wA, sc1W2, 0);
        for (int kc = 0; kc < 128; kc += 16) {
            LOADW8(wB, sc1W2, kc + 8);
            SC1_HALF(acc4, workS, AS, wA, kc);
            if (kc + 16 < 128) { LOADW8(wA, sc1W2, kc + 16); }
            SC1_HALF(acc4, workS, AS, wB, kc + 8);
        }
        if (w == 0) {
#pragma unroll
            for (int p = 0; p < 2; p++) {
                float xs[4];
#pragma unroll
                for (int j = 0; j < 4; j++) xs[j] = acc4[p][j] + sc1b2[cb + j];
                *(float4*)&xinS[(ry + 4 * p) * XS + cb] = *(float4*)xs;
            }
        } else {
#pragma unroll
            for (int p = 0; p < 2; p++)
#pragma unroll
                for (int j = 0; j < 4; j++) xg[p][j] = acc4[p][j] + sc1b2[cb + j];
        }
    }

    // ---- mix2: p[d][o] = sum_c gate[c]*vW[d][c]*mixW2[c][o] (wave 1) --------
    if (w == 1) {
#pragma unroll
        for (int p = 0; p < 2; p++) {
            float p0 = 0, p1 = 0, p2 = 0, p3 = 0, p4 = 0, p5 = 0;
#pragma unroll
            for (int c = 0; c < 4; c++) {
                float2 m = *(const float2*)(mixW2 + (size_t)(cb - 64 + c) * 2);
                const float v0 = xg[p][c] * acc[p][0][c];
                const float v1 = xg[p][c] * acc[p][1][c];
                const float v2 = xg[p][c] * acc[p][2][c];
                p0 += v0 * m.x; p1 += v0 * m.y;
                p2 += v1 * m.x; p3 += v1 * m.y;
                p4 += v2 * m.x; p5 += v2 * m.y;
            }
            RED16(p0); RED16(p1); RED16(p2); RED16(p3); RED16(p4); RED16(p5);
            if (cx == 0) {
                const int nl = ry + 4 * p;
                pwp[nl][0] = p0; pwp[nl][1] = p1;
                pwp[nl][2] = p2; pwp[nl][3] = p3;
                pwp[nl][4] = p4; pwp[nl][5] = p5;
            }
        }
    }
    __syncthreads();

    // ---- sc2 MLP: each wave handles 4 nodes in one shared 64-dot ------------
    {
        const float bb1 = sc2b1[ln];
        const float wn  = sc2W1[64 * 64 + ln];
        const float wq0 = sc2W2[ln * 2 + 0], wq1 = sc2W2[ln * 2 + 1];
        float vn2[4], g0[4], g1[4], g2[4];
#pragma unroll
        for (int r = 0; r < 4; r++) {
            const int nl = r * 2 + w;
            const float q00 = pwp[nl][0], q10 = pwp[nl][2], q20 = pwp[nl][4];
            vn2[r] = sqrtf(q00 * q00 + q10 * q10 + q20 * q20);
            g0[r] = pwp[nl][1]; g1[r] = pwp[nl][3]; g2[r] = pwp[nl][5];
            s1s[w][r][ln] = silu_f(xinS[nl * XS + ln]);
        }
        __builtin_amdgcn_s_waitcnt(0);
        float acc5[4];
#pragma unroll
        for (int r = 0; r < 4; r++) acc5[r] = bb1 + vn2[r] * wn;
#pragma unroll 8
        for (int i2 = 0; i2 < 64; i2++) {
            const float wv = sc2W1[i2 * 64 + ln];
#pragma unroll
            for (int r = 0; r < 4; r++) acc5[r] += s1s[w][r][i2] * wv;
        }
#pragma unroll
        for (int r = 0; r < 4; r++) {
            const float h2 = silu_f(acc5[r]);
            float q0 = h2 * wq0, q1 = h2 * wq1;
            RED64(q0); RED64(q1);
            if (ln == 0) {
                const int nl = r * 2 + w;
                const int n = node0 + nl;
                const float gate = q1 + sc2b2[1];
                const float l0o  = q0 + sc2b2[0];
                l0v[n] = l0o;
                l1v[(size_t)n * 3 + 0] = gate * g0[r];
                l1v[(size_t)n * 3 + 1] = gate * g1[r];
                l1v[(size_t)n * 3 + 2] = gate * g2[r];
                gateS[nl] = gate;
                l0S[nl]   = l0o;
            }
        }
    }
    __syncthreads();

    // ---- P-emit tail: 210 rows x 8 nodes (replaces pairpre_k) ---------------
    // Row layout matches pair_k: Pv rows 0..89 (a*30+h), Pr 90..179, Ps 180..209.
    {
        const int nl = t & 7;
        const int n  = node0 + nl;
        const float lj0 = gateS[nl] * pwp[nl][1];
        const float lj1 = gateS[nl] * pwp[nl][3];
        const float lj2 = gateS[nl] * pwp[nl][5];
        const float l0j = l0S[nl];
        const float pj0 = pos[n * 3 + 0], pj1 = pos[n * 3 + 1], pj2 = pos[n * 3 + 2];
#pragma unroll
        for (int it = 0; it < 14; it++) {
            const int row = (t >> 3) + it * 16;   // 0..223
            if (row < 210) {
                float val;
                if (row < 90) {
                    const int a = row / 30, h = row - a * 30;
                    val = lj0 * vvW1[(3 * a + 0) * 30 + h]
                        + lj1 * vvW1[(3 * a + 1) * 30 + h]
                        + lj2 * vvW1[(3 * a + 2) * 30 + h];
                } else if (row < 180) {
                    const int rr = row - 90;
                    const int a = rr / 30, h = rr - a * 30;
                    val = pj0 * vrW1[(3 * a + 0) * 30 + h]
                        + pj1 * vrW1[(3 * a + 1) * 30 + h]
                        + pj2 * vrW1[(3 * a + 2) * 30 + h];
                } else {
                    const int h = row - 180;
                    val = sb1[h] + l0j * sW1[30 + h];
                }
                P[(size_t)row * NNODES + n] = val;
            }
        }
    }
}

// ---------- pair kernel v4 (R3, known 88us): 4 i-atoms/thread ---------------
// Grid (A/8, B), 192 threads: t -> g=t/96, j=t%96; i = bx*8 + 4g + {0,1,2,3}.
__global__ __launch_bounds__(192)
void pair_k(const float* __restrict__ l0v, const float* __restrict__ l1v,
            const float* __restrict__ Pv, const float* __restrict__ Pr,
            const float* __restrict__ Ps,
            const float* __restrict__ vvb1, const float* __restrict__ vrb1,
            const float* __restrict__ sW1,
            const float* __restrict__ vvW2, const float* __restrict__ vrW2,
            const float* __restrict__ sW2,
            const float* __restrict__ vvb2, const float* __restrict__ vrb2,
            const float* __restrict__ sb2,
            const float* __restrict__ hW1,  const float* __restrict__ hb1,
            const float* __restrict__ hW2,  const float* __restrict__ hb2,
            float* __restrict__ out) {
    const int t = threadIdx.x;
    const int b = blockIdx.y;
    const int g = (t >= 96) ? 1 : 0;
    const int j = t - g * 96;
    const int i0 = blockIdx.x * 8 + g * 4;
    const int ni0 = b * A_ATOMS + i0;       // set A: ni0, ni0+1
    const int ni2 = ni0 + 2;                // set B: ni2, ni2+1
    const int nj  = b * A_ATOMS + j;

    const v2f liA0 = { l1v[ni0 * 3 + 0], l1v[(ni0 + 1) * 3 + 0] };
    const v2f liA1 = { l1v[ni0 * 3 + 1], l1v[(ni0 + 1) * 3 + 1] };
    const v2f liA2 = { l1v[ni0 * 3 + 2], l1v[(ni0 + 1) * 3 + 2] };
    const v2f s0iA = { l0v[ni0], l0v[ni0 + 1] };
    const v2f liB0 = { l1v[ni2 * 3 + 0], l1v[(ni2 + 1) * 3 + 0] };
    const v2f liB1 = { l1v[ni2 * 3 + 1], l1v[(ni2 + 1) * 3 + 1] };
    const v2f liB2 = { l1v[ni2 * 3 + 2], l1v[(ni2 + 1) * 3 + 2] };
    const v2f s0iB = { l0v[ni2], l0v[ni2 + 1] };

    v2f tA[9], tB[9];
#pragma unroll
    for (int l = 0; l < 9; l++) {
        const float t0 = vvb2[l] + vrb2[l] + sb2[l];
        tA[l] = (v2f)t0; tB[l] = (v2f)t0;
    }

#pragma unroll 2
    for (int h = 0; h < 30; h++) {
        const float pv0 = Pv[(size_t)h * NNODES + nj];
        const float pv1 = Pv[(size_t)(30 + h) * NNODES + nj];
        const float pv2 = Pv[(size_t)(60 + h) * NNODES + nj];
        const float pr0 = Pr[(size_t)h * NNODES + nj];
        const float pr1 = Pr[(size_t)(30 + h) * NNODES + nj];
        const float pr2 = Pr[(size_t)(60 + h) * NNODES + nj];
        const float ps  = Ps[(size_t)h * NNODES + nj];
        const float sw  = sW1[h];
        const float bv = vvb1[h], br = vrb1[h];

        v2f avA = (v2f)(bv) + liA0 * pv0 + liA1 * pv1 + liA2 * pv2;
        v2f arA = (v2f)(br) + liA0 * pr0 + liA1 * pr1 + liA2 * pr2;
        v2f asA = (v2f)(ps) + s0iA * sw;
        v2f avB = (v2f)(bv) + liB0 * pv0 + liB1 * pv1 + liB2 * pv2;
        v2f arB = (v2f)(br) + liB0 * pr0 + liB1 * pr1 + liB2 * pr2;
        v2f asB = (v2f)(ps) + s0iB * sw;
        avA = silu2(avA); arA = silu2(arA); asA = silu2(asA);
        avB = silu2(avB); arB = silu2(arB); asB = silu2(asB);
#pragma unroll
        for (int l = 0; l < 9; l++) {
            const float w2v = vvW2[h * 9 + l];
            const float w2r = vrW2[h * 9 + l];
            const float w2s = sW2[h * 9 + l];
            tA[l] += avA * w2v + arA * w2r + asA * w2s;
            tB[l] += avB * w2v + arB * w2r + asB * w2s;
        }
    }

    v2f oA[9], oB[9];
#pragma unroll
    for (int l = 0; l < 9; l++) {
        oA[l] = (v2f)(hb2[l]); oB[l] = (v2f)(hb2[l]);
    }
#pragma unroll 2
    for (int h = 0; h < 30; h++) {
        v2f aA = (v2f)(hb1[h]), aB = (v2f)(hb1[h]);
#pragma unroll
        for (int m = 0; m < 9; m++) {
            const float w1 = hW1[m * 30 + h];
            aA += tA[m] * w1; aB += tB[m] * w1;
        }
        aA = silu2(aA); aB = silu2(aB);
#pragma unroll
        for (int l = 0; l < 9; l++) {
            const float w2 = hW2[h * 9 + l];
            oA[l] += aA * w2; oB[l] += aB * w2;
        }
    }

    // out[((b*A+i)*3+k)*288 + j*3 + l]
#pragma unroll
    for (int k = 0; k < 3; k++) {
        const size_t offA0 = ((size_t)ni0 * 3 + k) * 288 + (size_t)j * 3;
        const size_t offA1 = offA0 + 3 * 288;
        out[offA0 + 0] = oA[3 * k + 0].x;
        out[offA0 + 1] = oA[3 * k + 1].x;
        out[offA0 + 2] = oA[3 * k + 2].x;
        out[offA1 + 0] = oA[3 * k + 0].y;
        out[offA1 + 1] = oA[3 * k + 1].y;
        out[offA1 + 2] = oA[3 * k + 2].y;
        const size_t offB0 = ((size_t)ni2 * 3 + k) * 288 + (size_t)j * 3;
        const size_t offB1 = offB0 + 3 * 288;
        out[offB0 + 0] = oB[3 * k + 0].x;
        out[offB0 + 1] = oB[3 * k + 1].x;
        out[offB0 + 2] = oB[3 * k + 2].x;
        out[offB1 + 0] = oB[3 * k + 0].y;
        out[offB1 + 1] = oB[3 * k + 1].y;
        out[offB1 + 2] = oB[3 * k + 2].y;
    }
}

extern "C" void kernel_launch(void* const* d_in, const int* in_sizes, int n_in,
                              void* d_out, int out_size, void* d_ws, size_t ws_size,
                              hipStream_t stream) {
    const float* pos   = (const float*)d_in[0];
    const float* srep  = (const float*)d_in[1];
    const float* vrep  = (const float*)d_in[2];
    const float* mixW1 = (const float*)d_in[3];
    const float* sc1W1 = (const float*)d_in[4];
    const float* sc1b1 = (const float*)d_in[5];
    const float* sc1W2 = (const float*)d_in[6];
    const float* sc1b2 = (const float*)d_in[7];
    const float* mixW2 = (const float*)d_in[8];
    const float* sc2W1 = (const float*)d_in[9];
    const float* sc2b1 = (const float*)d_in[10];
    const float* sc2W2 = (const float*)d_in[11];
    const float* sc2b2 = (const float*)d_in[12];
    const float* vvW1  = (const float*)d_in[13];
    const float* vvb1  = (const float*)d_in[14];
    const float* vvW2  = (const float*)d_in[15];
    const float* vvb2  = (const float*)d_in[16];
    const float* vrW1  = (const float*)d_in[17];
    const float* vrb1  = (const float*)d_in[18];
    const float* vrW2  = (const float*)d_in[19];
    const float* vrb2  = (const float*)d_in[20];
    const float* sW1   = (const float*)d_in[21];
    const float* sb1   = (const float*)d_in[22];
    const float* sW2   = (const float*)d_in[23];
    const float* sb2   = (const float*)d_in[24];
    const float* hW1   = (const float*)d_in[25];
    const float* hb1   = (const float*)d_in[26];
    const float* hW2   = (const float*)d_in[27];
    const float* hb2   = (const float*)d_in[28];

    float* ws  = (float*)d_ws;
    float* P   = ws;                               // 210*NNODES floats
    float* Pv  = P;                                // rows   0..89
    float* Pr  = P + (size_t)90  * NNODES;         // rows  90..179
    float* Ps  = P + (size_t)180 * NNODES;         // rows 180..209
    float* l0v = P + (size_t)210 * NNODES;         // 12,288
    float* l1v = l0v + NNODES;                     // 36,864
    float* outf = (float*)d_out;

    // 1. fused node stage -> l0, l1, P (pairpre folded in)
    node_k<<<NNODES / NB, 128, 0, stream>>>(
        vrep, mixW1, srep,
        sc1W1, sc1b1, sc1W2, sc1b2,
        mixW2, sc2W1, sc2b1, sc2W2, sc2b2,
        pos, vvW1, vrW1, sW1, sb1,
        l0v, l1v, P);

    // 2. pair stage (4 i per thread, packed f32)
    pair_k<<<dim3(A_ATOMS / 8, BATCH), 192, 0, stream>>>(
        l0v, l1v, Pv, Pr, Ps,
        vvb1, vrb1, sW1,
        vvW2, vrW2, sW2,
        vvb2, vrb2, sb2,
        hW1, hb1, hW2, hb2,
        outf);
}

// Round 7
// 261.812 us; speedup vs baseline: 1.1045x; 1.0322x over previous
//
#include <hip/hip_runtime.h>
#include <cstddef>

#define A_ATOMS 96
#define BATCH   128
#define NNODES  12288   // B*A
#define NB      8       // nodes per block (node_k)
#define AS      132     // AsL / workS stride (132%32=4)
#define XS      196     // xinS stride (196%32=4)
#define PSTR    240     // P row stride per node: 30 h * 8 floats (960 B, 16B-aligned)

typedef float v2f __attribute__((ext_vector_type(2)));

__device__ __forceinline__ float silu_f(float x) {
    float e = __expf(-x);
    return x * __builtin_amdgcn_rcpf(1.0f + e);
}
__device__ __forceinline__ v2f silu2(v2f x) {
    v2f r; r.x = silu_f(x.x); r.y = silu_f(x.y); return r;
}

#define RED64(v) { v += __shfl_xor(v, 1); v += __shfl_xor(v, 2); v += __shfl_xor(v, 4); \
                   v += __shfl_xor(v, 8); v += __shfl_xor(v, 16); v += __shfl_xor(v, 32); }
#define RED16(v) { v += __shfl_xor(v, 1); v += __shfl_xor(v, 2); v += __shfl_xor(v, 4); \
                   v += __shfl_xor(v, 8); }

// ===== fused node kernel: exact R2 body (measured ~65us) + P-emit tail ======
// 128 threads, 2 nodes/thread. NO explicit weight prefetch (R4/R6 lesson:
// macro ping-pong buffers hurt; compiler schedule + TLP wins).
// Tail emits P in [node][h][8] layout for pair_k's imm-offset float4 loads.
__global__ __launch_bounds__(128, 3)
void node_k(const float* __restrict__ vrep, const float* __restrict__ mixW1,
            const float* __restrict__ srep,
            const float* __restrict__ sc1W1, const float* __restrict__ sc1b1,
            const float* __restrict__ sc1W2, const float* __restrict__ sc1b2,
            const float* __restrict__ mixW2,
            const float* __restrict__ sc2W1, const float* __restrict__ sc2b1,
            const float* __restrict__ sc2W2, const float* __restrict__ sc2b2,
            const float* __restrict__ pos,
            const float* __restrict__ vvW1, const float* __restrict__ vrW1,
            const float* __restrict__ sW1,  const float* __restrict__ sb1,
            float* __restrict__ l0v, float* __restrict__ l1v,
            float* __restrict__ P) {
    __shared__ float AsL[24 * AS];
    __shared__ float xinS[NB * XS];
    __shared__ float s1s[2][4][64];
    __shared__ float pwp[NB][6];
    __shared__ float gateS[NB], l0S[NB];

    const int t  = threadIdx.x;
    const int w  = t >> 6;
    const int ln = t & 63;
    const int cx = ln & 15;
    const int ry = ln >> 4;
    const int cb = w * 64 + cx * 4;
    const int row0  = blockIdx.x * 24;
    const int node0 = blockIdx.x * NB;

#pragma unroll
    for (int it = 0; it < 6; it++) {
        const int idx = it * 128 + t;
        const int r   = idx >> 5;
        const int c4  = (idx & 31) * 4;
        *(float4*)&AsL[r * AS + c4] = *(const float4*)(vrep + (size_t)(row0 + r) * 128 + c4);
    }
#pragma unroll
    for (int it = 0; it < 2; it++) {
        const int idx = it * 128 + t;
        const int a   = idx >> 5;
        const int c4  = (idx & 31) * 4;
        *(float4*)&xinS[a * XS + c4] = *(const float4*)(srep + (size_t)(node0 + a) * 128 + c4);
    }
    __syncthreads();

    // ---- mix1: vmix[2 nodes][3 dims][4 cols] --------------------------------
    float acc[2][3][4];
#pragma unroll
    for (int p = 0; p < 2; p++)
#pragma unroll
        for (int d = 0; d < 3; d++)
#pragma unroll
            for (int j = 0; j < 4; j++) acc[p][d][j] = 0.0f;

    for (int kc = 0; kc < 128; kc += 8) {
        float a[2][3][8];
#pragma unroll
        for (int p = 0; p < 2; p++)
#pragma unroll
            for (int d = 0; d < 3; d++) {
                const int row = (3 * (ry + 4 * p) + d) * AS + kc;
                *(float4*)&a[p][d][0] = *(const float4*)&AsL[row];
                *(float4*)&a[p][d][4] = *(const float4*)&AsL[row + 4];
            }
#pragma unroll
        for (int kk = 0; kk < 8; kk++) {
            float b[4];
            *(float4*)b = *(const float4*)(mixW1 + (size_t)(kc + kk) * 128 + cb);
#pragma unroll
            for (int p = 0; p < 2; p++)
#pragma unroll
                for (int d = 0; d < 3; d++)
#pragma unroll
                    for (int j = 0; j < 4; j++)
                        acc[p][d][j] += a[p][d][kk] * b[j];
        }
    }
    if (w == 0) {
#pragma unroll
        for (int p = 0; p < 2; p++) {
            float nrm[4];
#pragma unroll
            for (int c = 0; c < 4; c++)
                nrm[c] = sqrtf(acc[p][0][c] * acc[p][0][c] + acc[p][1][c] * acc[p][1][c]
                             + acc[p][2][c] * acc[p][2][c]);
            *(float4*)&xinS[(ry + 4 * p) * XS + 128 + cb] = *(float4*)nrm;
        }
    }
    __syncthreads();

    // ---- sc1 layer 1: xin(192) @ sc1W1(192x128) -> silu ---------------------
    float* workS = AsL;
    {
        float acc3[2][4];
#pragma unroll
        for (int p = 0; p < 2; p++)
#pragma unroll
            for (int j = 0; j < 4; j++) acc3[p][j] = 0.0f;
        for (int kc = 0; kc < 192; kc += 8) {
            float af[2][8];
#pragma unroll
            for (int p = 0; p < 2; p++) {
                const int row = (ry + 4 * p) * XS + kc;
                *(float4*)&af[p][0] = *(const float4*)&xinS[row];
                *(float4*)&af[p][4] = *(const float4*)&xinS[row + 4];
            }
#pragma unroll
            for (int kk = 0; kk < 8; kk++) {
                float b[4];
                *(float4*)b = *(const float4*)(sc1W1 + (size_t)(kc + kk) * 128 + cb);
#pragma unroll
                for (int p = 0; p < 2; p++)
#pragma unroll
                    for (int j = 0; j < 4; j++) acc3[p][j] += af[p][kk] * b[j];
            }
        }
#pragma unroll
        for (int p = 0; p < 2; p++) {
            float h[4];
#pragma unroll
            for (int j = 0; j < 4; j++) h[j] = silu_f(acc3[p][j] + sc1b1[cb + j]);
            *(float4*)&workS[(ry + 4 * p) * AS + cb] = *(float4*)h;
        }
    }
    __syncthreads();

    // ---- sc1 layer 2: h(128) @ sc1W2(128x128) -------------------------------
    float xg[2][4];
    {
        float acc4[2][4];
#pragma unroll
        for (int p = 0; p < 2; p++)
#pragma unroll
            for (int j = 0; j < 4; j++) acc4[p][j] = 0.0f;
        for (int kc = 0; kc < 128; kc += 8) {
            float af[2][8];
#pragma unroll
            for (int p = 0; p < 2; p++) {
                const int row = (ry + 4 * p) * AS + kc;
                *(float4*)&af[p][0] = *(const float4*)&workS[row];
                *(float4*)&af[p][4] = *(const float4*)&workS[row + 4];
            }
#pragma unroll
            for (int kk = 0; kk < 8; kk++) {
                float b[4];
                *(float4*)b = *(const float4*)(sc1W2 + (size_t)(kc + kk) * 128 + cb);
#pragma unroll
                for (int p = 0; p < 2; p++)
#pragma unroll
                    for (int j = 0; j < 4; j++) acc4[p][j] += af[p][kk] * b[j];
            }
        }
        if (w == 0) {
#pragma unroll
            for (int p = 0; p < 2; p++) {
                float xs[4];
#pragma unroll
                for (int j = 0; j < 4; j++) xs[j] = acc4[p][j] + sc1b2[cb + j];
                *(float4*)&xinS[(ry + 4 * p) * XS + cb] = *(float4*)xs;
            }
        } else {
#pragma unroll
            for (int p = 0; p < 2; p++)
#pragma unroll
                for (int j = 0; j < 4; j++) xg[p][j] = acc4[p][j] + sc1b2[cb + j];
        }
    }

    // ---- mix2: p[d][o] = sum_c gate[c]*vW[d][c]*mixW2[c][o] (wave 1) --------
    if (w == 1) {
#pragma unroll
        for (int p = 0; p < 2; p++) {
            float p0 = 0, p1 = 0, p2 = 0, p3 = 0, p4 = 0, p5 = 0;
#pragma unroll
            for (int c = 0; c < 4; c++) {
                float2 m = *(const float2*)(mixW2 + (size_t)(cb - 64 + c) * 2);
                const float v0 = xg[p][c] * acc[p][0][c];
                const float v1 = xg[p][c] * acc[p][1][c];
                const float v2 = xg[p][c] * acc[p][2][c];
                p0 += v0 * m.x; p1 += v0 * m.y;
                p2 += v1 * m.x; p3 += v1 * m.y;
                p4 += v2 * m.x; p5 += v2 * m.y;
            }
            RED16(p0); RED16(p1); RED16(p2); RED16(p3); RED16(p4); RED16(p5);
            if (cx == 0) {
                const int nl = ry + 4 * p;
                pwp[nl][0] = p0; pwp[nl][1] = p1;
                pwp[nl][2] = p2; pwp[nl][3] = p3;
                pwp[nl][4] = p4; pwp[nl][5] = p5;
            }
        }
    }
    __syncthreads();

    // ---- sc2 MLP: each wave handles 4 nodes in one shared 64-dot ------------
    {
        const float bb1 = sc2b1[ln];
        const float wn  = sc2W1[64 * 64 + ln];
        const float wq0 = sc2W2[ln * 2 + 0], wq1 = sc2W2[ln * 2 + 1];
        float vn2[4], g0[4], g1[4], g2[4];
#pragma unroll
        for (int r = 0; r < 4; r++) {
            const int nl = r * 2 + w;
            const float q00 = pwp[nl][0], q10 = pwp[nl][2], q20 = pwp[nl][4];
            vn2[r] = sqrtf(q00 * q00 + q10 * q10 + q20 * q20);
            g0[r] = pwp[nl][1]; g1[r] = pwp[nl][3]; g2[r] = pwp[nl][5];
            s1s[w][r][ln] = silu_f(xinS[nl * XS + ln]);
        }
        __builtin_amdgcn_s_waitcnt(0);
        float acc5[4];
#pragma unroll
        for (int r = 0; r < 4; r++) acc5[r] = bb1 + vn2[r] * wn;
#pragma unroll 8
        for (int i2 = 0; i2 < 64; i2++) {
            const float wv = sc2W1[i2 * 64 + ln];
#pragma unroll
            for (int r = 0; r < 4; r++) acc5[r] += s1s[w][r][i2] * wv;
        }
#pragma unroll
        for (int r = 0; r < 4; r++) {
            const float h2 = silu_f(acc5[r]);
            float q0 = h2 * wq0, q1 = h2 * wq1;
            RED64(q0); RED64(q1);
            if (ln == 0) {
                const int nl = r * 2 + w;
                const int n = node0 + nl;
                const float gate = q1 + sc2b2[1];
                const float l0o  = q0 + sc2b2[0];
                l0v[n] = l0o;
                l1v[(size_t)n * 3 + 0] = gate * g0[r];
                l1v[(size_t)n * 3 + 1] = gate * g1[r];
                l1v[(size_t)n * 3 + 2] = gate * g2[r];
                gateS[nl] = gate;
                l0S[nl]   = l0o;
            }
        }
    }
    __syncthreads();

    // ---- P-emit tail: layout [node][h<30][8] = {pv0,pv1,pv2,pr0,pr1,pr2,ps,0}
    // 16 threads per node; thread q covers h = q and q+16.
    {
        const int nl = t >> 4;          // 0..7
        const int q  = t & 15;          // 0..15
        const int n  = node0 + nl;
        const float lj0 = gateS[nl] * pwp[nl][1];
        const float lj1 = gateS[nl] * pwp[nl][3];
        const float lj2 = gateS[nl] * pwp[nl][5];
        const float l0j = l0S[nl];
        const float pj0 = pos[n * 3 + 0], pj1 = pos[n * 3 + 1], pj2 = pos[n * 3 + 2];
        float* Pj = P + (size_t)n * PSTR;
        for (int h = q; h < 30; h += 16) {
            float o[8];
#pragma unroll
            for (int a = 0; a < 3; a++) {
                o[a]     = lj0 * vvW1[(3 * a + 0) * 30 + h]
                         + lj1 * vvW1[(3 * a + 1) * 30 + h]
                         + lj2 * vvW1[(3 * a + 2) * 30 + h];
                o[3 + a] = pj0 * vrW1[(3 * a + 0) * 30 + h]
                         + pj1 * vrW1[(3 * a + 1) * 30 + h]
                         + pj2 * vrW1[(3 * a + 2) * 30 + h];
            }
            o[6] = sb1[h] + l0j * sW1[30 + h];
            o[7] = 0.0f;
            *(float4*)&Pj[h * 8 + 0] = *(float4*)&o[0];
            *(float4*)&Pj[h * 8 + 4] = *(float4*)&o[4];
        }
    }
}

// ---------- pair kernel v6: R3 schedule + [nj][h][8] float4 P-loads ---------
// Grid (A/8, B), 192 threads: t -> g=t/96, j=t%96; i = bx*8 + 4g + {0,1,2,3}.
// One base pointer per thread; all 60 P-loads are float4 at imm offsets
// (h*32 B) -> zero per-load address math, 210 -> 60 load instructions.
__global__ __launch_bounds__(192)
void pair_k(const float* __restrict__ l0v, const float* __restrict__ l1v,
            const float* __restrict__ P,
            const float* __restrict__ vvb1, const float* __restrict__ vrb1,
            const float* __restrict__ sW1,
            const float* __restrict__ vvW2, const float* __restrict__ vrW2,
            const float* __restrict__ sW2,
            const float* __restrict__ vvb2, const float* __restrict__ vrb2,
            const float* __restrict__ sb2,
            const float* __restrict__ hW1,  const float* __restrict__ hb1,
            const float* __restrict__ hW2,  const float* __restrict__ hb2,
            float* __restrict__ out) {
    const int t = threadIdx.x;
    const int b = blockIdx.y;
    const int g = (t >= 96) ? 1 : 0;
    const int j = t - g * 96;
    const int i0 = blockIdx.x * 8 + g * 4;
    const int ni0 = b * A_ATOMS + i0;       // set A: ni0, ni0+1
    const int ni2 = ni0 + 2;                // set B: ni2, ni2+1
    const int nj  = b * A_ATOMS + j;
    const float* Pj = P + (size_t)nj * PSTR;

    const v2f liA0 = { l1v[ni0 * 3 + 0], l1v[(ni0 + 1) * 3 + 0] };
    const v2f liA1 = { l1v[ni0 * 3 + 1], l1v[(ni0 + 1) * 3 + 1] };
    const v2f liA2 = { l1v[ni0 * 3 + 2], l1v[(ni0 + 1) * 3 + 2] };
    const v2f s0iA = { l0v[ni0], l0v[ni0 + 1] };
    const v2f liB0 = { l1v[ni2 * 3 + 0], l1v[(ni2 + 1) * 3 + 0] };
    const v2f liB1 = { l1v[ni2 * 3 + 1], l1v[(ni2 + 1) * 3 + 1] };
    const v2f liB2 = { l1v[ni2 * 3 + 2], l1v[(ni2 + 1) * 3 + 2] };
    const v2f s0iB = { l0v[ni2], l0v[ni2 + 1] };

    v2f tA[9], tB[9];
#pragma unroll
    for (int l = 0; l < 9; l++) {
        const float t0 = vvb2[l] + vrb2[l] + sb2[l];
        tA[l] = (v2f)t0; tB[l] = (v2f)t0;
    }

#pragma unroll 2
    for (int h = 0; h < 30; h++) {
        const float4 w0 = *(const float4*)&Pj[h * 8 + 0];
        const float4 w1 = *(const float4*)&Pj[h * 8 + 4];
        const float pv0 = w0.x, pv1 = w0.y, pv2 = w0.z;
        const float pr0 = w0.w, pr1 = w1.x, pr2 = w1.y;
        const float ps  = w1.z;
        const float sw  = sW1[h];
        const float bv = vvb1[h], br = vrb1[h];

        v2f avA = (v2f)(bv) + liA0 * pv0 + liA1 * pv1 + liA2 * pv2;
        v2f arA = (v2f)(br) + liA0 * pr0 + liA1 * pr1 + liA2 * pr2;
        v2f asA = (v2f)(ps) + s0iA * sw;
        v2f avB = (v2f)(bv) + liB0 * pv0 + liB1 * pv1 + liB2 * pv2;
        v2f arB = (v2f)(br) + liB0 * pr0 + liB1 * pr1 + liB2 * pr2;
        v2f asB = (v2f)(ps) + s0iB * sw;
        avA = silu2(avA); arA = silu2(arA); asA = silu2(asA);
        avB = silu2(avB); arB = silu2(arB); asB = silu2(asB);
#pragma unroll
        for (int l = 0; l < 9; l++) {
            const float w2v = vvW2[h * 9 + l];
            const float w2r = vrW2[h * 9 + l];
            const float w2s = sW2[h * 9 + l];
            tA[l] += avA * w2v + arA * w2r + asA * w2s;
            tB[l] += avB * w2v + arB * w2r + asB * w2s;
        }
    }

    v2f oA[9], oB[9];
#pragma unroll
    for (int l = 0; l < 9; l++) {
        oA[l] = (v2f)(hb2[l]); oB[l] = (v2f)(hb2[l]);
    }
#pragma unroll 2
    for (int h = 0; h < 30; h++) {
        v2f aA = (v2f)(hb1[h]), aB = (v2f)(hb1[h]);
#pragma unroll
        for (int m = 0; m < 9; m++) {
            const float w1 = hW1[m * 30 + h];
            aA += tA[m] * w1; aB += tB[m] * w1;
        }
        aA = silu2(aA); aB = silu2(aB);
#pragma unroll
        for (int l = 0; l < 9; l++) {
            const float w2 = hW2[h * 9 + l];
            oA[l] += aA * w2; oB[l] += aB * w2;
        }
    }

    // out[((b*A+i)*3+k)*288 + j*3 + l]
#pragma unroll
    for (int k = 0; k < 3; k++) {
        const size_t offA0 = ((size_t)ni0 * 3 + k) * 288 + (size_t)j * 3;
        const size_t offA1 = offA0 + 3 * 288;
        out[offA0 + 0] = oA[3 * k + 0].x;
        out[offA0 + 1] = oA[3 * k + 1].x;
        out[offA0 + 2] = oA[3 * k + 2].x;
        out[offA1 + 0] = oA[3 * k + 0].y;
        out[offA1 + 1] = oA[3 * k + 1].y;
        out[offA1 + 2] = oA[3 * k + 2].y;
        const size_t offB0 = ((size_t)ni2 * 3 + k) * 288 + (size_t)j * 3;
        const size_t offB1 = offB0 + 3 * 288;
        out[offB0 + 0] = oB[3 * k + 0].x;
        out[offB0 + 1] = oB[3 * k + 1].x;
        out[offB0 + 2] = oB[3 * k + 2].x;
        out[offB1 + 0] = oB[3 * k + 0].y;
        out[offB1 + 1] = oB[3 * k + 1].y;
        out[offB1 + 2] = oB[3 * k + 2].y;
    }
}

extern "C" void kernel_launch(void* const* d_in, const int* in_sizes, int n_in,
                              void* d_out, int out_size, void* d_ws, size_t ws_size,
                              hipStream_t stream) {
    const float* pos   = (const float*)d_in[0];
    const float* srep  = (const float*)d_in[1];
    const float* vrep  = (const float*)d_in[2];
    const float* mixW1 = (const float*)d_in[3];
    const float* sc1W1 = (const float*)d_in[4];
    const float* sc1b1 = (const float*)d_in[5];
    const float* sc1W2 = (const float*)d_in[6];
    const float* sc1b2 = (const float*)d_in[7];
    const float* mixW2 = (const float*)d_in[8];
    const float* sc2W1 = (const float*)d_in[9];
    const float* sc2b1 = (const float*)d_in[10];
    const float* sc2W2 = (const float*)d_in[11];
    const float* sc2b2 = (const float*)d_in[12];
    const float* vvW1  = (const float*)d_in[13];
    const float* vvb1  = (const float*)d_in[14];
    const float* vvW2  = (const float*)d_in[15];
    const float* vvb2  = (const float*)d_in[16];
    const float* vrW1  = (const float*)d_in[17];
    const float* vrb1  = (const float*)d_in[18];
    const float* vrW2  = (const float*)d_in[19];
    const float* vrb2  = (const float*)d_in[20];
    const float* sW1   = (const float*)d_in[21];
    const float* sb1   = (const float*)d_in[22];
    const float* sW2   = (const float*)d_in[23];
    const float* sb2   = (const float*)d_in[24];
    const float* hW1   = (const float*)d_in[25];
    const float* hb1   = (const float*)d_in[26];
    const float* hW2   = (const float*)d_in[27];
    const float* hb2   = (const float*)d_in[28];

    float* ws  = (float*)d_ws;
    float* P   = ws;                               // PSTR*NNODES = 2,949,120 floats
    float* l0v = P + (size_t)PSTR * NNODES;        // 12,288
    float* l1v = l0v + NNODES;                     // 36,864
    float* outf = (float*)d_out;

    // 1. fused node stage -> l0, l1, P
    node_k<<<NNODES / NB, 128, 0, stream>>>(
        vrep, mixW1, srep,
        sc1W1, sc1b1, sc1W2, sc1b2,
        mixW2, sc2W1, sc2b1, sc2W2, sc2b2,
        pos, vvW1, vrW1, sW1, sb1,
        l0v, l1v, P);

    // 2. pair stage (4 i per thread, imm-offset float4 P-loads)
    pair_k<<<dim3(A_ATOMS / 8, BATCH), 192, 0, stream>>>(
        l0v, l1v, P,
        vvb1, vrb1, sW1,
        vvW2, vrW2, sW2,
        vvb2, vrb2, sb2,
        hW1, hb1, hW2, hb2,
        outf);
}

// Round 9
// 258.948 us; speedup vs baseline: 1.1168x; 1.0111x over previous
//
#include <hip/hip_runtime.h>
#include <cstddef>

#define A_ATOMS 96
#define BATCH   128
#define NNODES  12288   // B*A
#define NB      8       // nodes per block (node_k)
#define AS      132     // AsL / workS stride (132%32=4)
#define XS      196     // xinS stride (196%32=4)
#define PSTR    240     // P row stride per node: 30 h * 8 floats

typedef float v2f __attribute__((ext_vector_type(2)));
typedef unsigned long long u64;

__device__ __forceinline__ float silu_f(float x) {
    float e = __expf(-x);
    return x * __builtin_amdgcn_rcpf(1.0f + e);
}

// ---- packed f32 FMA (CDNA VOP3P, full-rate 2xFMA): acc = a*w + acc ---------
// w is a wave-uniform 64-bit weight pair -> SGPR operand (1 const-bus slot).
// _lo/_hi broadcast the low/high half of `a` to both lanes via op_sel.
__device__ __forceinline__ void pkfma(v2f& acc, v2f a, u64 w) {
    asm("v_pk_fma_f32 %0, %1, %2, %0" : "+v"(acc) : "v"(a), "s"(w));
}
__device__ __forceinline__ void pkfma_lo(v2f& acc, v2f a, u64 w) {
    asm("v_pk_fma_f32 %0, %1, %2, %0 op_sel:[0,0,0] op_sel_hi:[0,1,1]"
        : "+v"(acc) : "v"(a), "s"(w));
}
__device__ __forceinline__ void pkfma_hi(v2f& acc, v2f a, u64 w) {
    asm("v_pk_fma_f32 %0, %1, %2, %0 op_sel:[1,0,0] op_sel_hi:[1,1,1]"
        : "+v"(acc) : "v"(a), "s"(w));
}
__device__ __forceinline__ u64 ldw2(const float* p) {
    u64 w; __builtin_memcpy(&w, p, 8); return w;   // 4B-aligned-safe pair load
}

#define RED64(v) { v += __shfl_xor(v, 1); v += __shfl_xor(v, 2); v += __shfl_xor(v, 4); \
                   v += __shfl_xor(v, 8); v += __shfl_xor(v, 16); v += __shfl_xor(v, 32); }
#define RED16(v) { v += __shfl_xor(v, 1); v += __shfl_xor(v, 2); v += __shfl_xor(v, 4); \
                   v += __shfl_xor(v, 8); }

// ===== fused node kernel: R7 version unchanged (R2 body + P-emit tail) ======
__global__ __launch_bounds__(128, 3)
void node_k(const float* __restrict__ vrep, const float* __restrict__ mixW1,
            const float* __restrict__ srep,
            const float* __restrict__ sc1W1, const float* __restrict__ sc1b1,
            const float* __restrict__ sc1W2, const float* __restrict__ sc1b2,
            const float* __restrict__ mixW2,
            const float* __restrict__ sc2W1, const float* __restrict__ sc2b1,
            const float* __restrict__ sc2W2, const float* __restrict__ sc2b2,
            const float* __restrict__ pos,
            const float* __restrict__ vvW1, const float* __restrict__ vrW1,
            const float* __restrict__ sW1,  const float* __restrict__ sb1,
            float* __restrict__ l0v, float* __restrict__ l1v,
            float* __restrict__ P) {
    __shared__ float AsL[24 * AS];
    __shared__ float xinS[NB * XS];
    __shared__ float s1s[2][4][64];
    __shared__ float pwp[NB][6];
    __shared__ float gateS[NB], l0S[NB];

    const int t  = threadIdx.x;
    const int w  = t >> 6;
    const int ln = t & 63;
    const int cx = ln & 15;
    const int ry = ln >> 4;
    const int cb = w * 64 + cx * 4;
    const int row0  = blockIdx.x * 24;
    const int node0 = blockIdx.x * NB;

#pragma unroll
    for (int it = 0; it < 6; it++) {
        const int idx = it * 128 + t;
        const int r   = idx >> 5;
        const int c4  = (idx & 31) * 4;
        *(float4*)&AsL[r * AS + c4] = *(const float4*)(vrep + (size_t)(row0 + r) * 128 + c4);
    }
#pragma unroll
    for (int it = 0; it < 2; it++) {
        const int idx = it * 128 + t;
        const int a   = idx >> 5;
        const int c4  = (idx & 31) * 4;
        *(float4*)&xinS[a * XS + c4] = *(const float4*)(srep + (size_t)(node0 + a) * 128 + c4);
    }
    __syncthreads();

    float acc[2][3][4];
#pragma unroll
    for (int p = 0; p < 2; p++)
#pragma unroll
        for (int d = 0; d < 3; d++)
#pragma unroll
            for (int j = 0; j < 4; j++) acc[p][d][j] = 0.0f;

    for (int kc = 0; kc < 128; kc += 8) {
        float a[2][3][8];
#pragma unroll
        for (int p = 0; p < 2; p++)
#pragma unroll
            for (int d = 0; d < 3; d++) {
                const int row = (3 * (ry + 4 * p) + d) * AS + kc;
                *(float4*)&a[p][d][0] = *(const float4*)&AsL[row];
                *(float4*)&a[p][d][4] = *(const float4*)&AsL[row + 4];
            }
#pragma unroll
        for (int kk = 0; kk < 8; kk++) {
            float b[4];
            *(float4*)b = *(const float4*)(mixW1 + (size_t)(kc + kk) * 128 + cb);
#pragma unroll
            for (int p = 0; p < 2; p++)
#pragma unroll
                for (int d = 0; d < 3; d++)
#pragma unroll
                    for (int j = 0; j < 4; j++)
                        acc[p][d][j] += a[p][d][kk] * b[j];
        }
    }
    if (w == 0) {
#pragma unroll
        for (int p = 0; p < 2; p++) {
            float nrm[4];
#pragma unroll
            for (int c = 0; c < 4; c++)
                nrm[c] = sqrtf(acc[p][0][c] * acc[p][0][c] + acc[p][1][c] * acc[p][1][c]
                             + acc[p][2][c] * acc[p][2][c]);
            *(float4*)&xinS[(ry + 4 * p) * XS + 128 + cb] = *(float4*)nrm;
        }
    }
    __syncthreads();

    float* workS = AsL;
    {
        float acc3[2][4];
#pragma unroll
        for (int p = 0; p < 2; p++)
#pragma unroll
            for (int j = 0; j < 4; j++) acc3[p][j] = 0.0f;
        for (int kc = 0; kc < 192; kc += 8) {
            float af[2][8];
#pragma unroll
            for (int p = 0; p < 2; p++) {
                const int row = (ry + 4 * p) * XS + kc;
                *(float4*)&af[p][0] = *(const float4*)&xinS[row];
                *(float4*)&af[p][4] = *(const float4*)&xinS[row + 4];
            }
#pragma unroll
            for (int kk = 0; kk < 8; kk++) {
                float b[4];
                *(float4*)b = *(const float4*)(sc1W1 + (size_t)(kc + kk) * 128 + cb);
#pragma unroll
                for (int p = 0; p < 2; p++)
#pragma unroll
                    for (int j = 0; j < 4; j++) acc3[p][j] += af[p][kk] * b[j];
            }
        }
#pragma unroll
        for (int p = 0; p < 2; p++) {
            float h[4];
#pragma unroll
            for (int j = 0; j < 4; j++) h[j] = silu_f(acc3[p][j] + sc1b1[cb + j]);
            *(float4*)&workS[(ry + 4 * p) * AS + cb] = *(float4*)h;
        }
    }
    __syncthreads();

    float xg[2][4];
    {
        float acc4[2][4];
#pragma unroll
        for (int p = 0; p < 2; p++)
#pragma unroll
            for (int j = 0; j < 4; j++) acc4[p][j] = 0.0f;
        for (int kc = 0; kc < 128; kc += 8) {
            float af[2][8];
#pragma unroll
            for (int p = 0; p < 2; p++) {
                const int row = (ry + 4 * p) * AS + kc;
                *(float4*)&af[p][0] = *(const float4*)&workS[row];
                *(float4*)&af[p][4] = *(const float4*)&workS[row + 4];
            }
#pragma unroll
            for (int kk = 0; kk < 8; kk++) {
                float b[4];
                *(float4*)b = *(const float4*)(sc1W2 + (size_t)(kc + kk) * 128 + cb);
#pragma unroll
                for (int p = 0; p < 2; p++)
#pragma unroll
                    for (int j = 0; j < 4; j++) acc4[p][j] += af[p][kk] * b[j];
            }
        }
        if (w == 0) {
#pragma unroll
            for (int p = 0; p < 2; p++) {
                float xs[4];
#pragma unroll
                for (int j = 0; j < 4; j++) xs[j] = acc4[p][j] + sc1b2[cb + j];
                *(float4*)&xinS[(ry + 4 * p) * XS + cb] = *(float4*)xs;
            }
        } else {
#pragma unroll
            for (int p = 0; p < 2; p++)
#pragma unroll
                for (int j = 0; j < 4; j++) xg[p][j] = acc4[p][j] + sc1b2[cb + j];
        }
    }

    if (w == 1) {
#pragma unroll
        for (int p = 0; p < 2; p++) {
            float p0 = 0, p1 = 0, p2 = 0, p3 = 0, p4 = 0, p5 = 0;
#pragma unroll
            for (int c = 0; c < 4; c++) {
                float2 m = *(const float2*)(mixW2 + (size_t)(cb - 64 + c) * 2);
                const float v0 = xg[p][c] * acc[p][0][c];
                const float v1 = xg[p][c] * acc[p][1][c];
                const float v2 = xg[p][c] * acc[p][2][c];
                p0 += v0 * m.x; p1 += v0 * m.y;
                p2 += v1 * m.x; p3 += v1 * m.y;
                p4 += v2 * m.x; p5 += v2 * m.y;
            }
            RED16(p0); RED16(p1); RED16(p2); RED16(p3); RED16(p4); RED16(p5);
            if (cx == 0) {
                const int nl = ry + 4 * p;
                pwp[nl][0] = p0; pwp[nl][1] = p1;
                pwp[nl][2] = p2; pwp[nl][3] = p3;
                pwp[nl][4] = p4; pwp[nl][5] = p5;
            }
        }
    }
    __syncthreads();

    {
        const float bb1 = sc2b1[ln];
        const float wn  = sc2W1[64 * 64 + ln];
        const float wq0 = sc2W2[ln * 2 + 0], wq1 = sc2W2[ln * 2 + 1];
        float vn2[4], g0[4], g1[4], g2[4];
#pragma unroll
        for (int r = 0; r < 4; r++) {
            const int nl = r * 2 + w;
            const float q00 = pwp[nl][0], q10 = pwp[nl][2], q20 = pwp[nl][4];
            vn2[r] = sqrtf(q00 * q00 + q10 * q10 + q20 * q20);
            g0[r] = pwp[nl][1]; g1[r] = pwp[nl][3]; g2[r] = pwp[nl][5];
            s1s[w][r][ln] = silu_f(xinS[nl * XS + ln]);
        }
        __builtin_amdgcn_s_waitcnt(0);
        float acc5[4];
#pragma unroll
        for (int r = 0; r < 4; r++) acc5[r] = bb1 + vn2[r] * wn;
#pragma unroll 8
        for (int i2 = 0; i2 < 64; i2++) {
            const float wv = sc2W1[i2 * 64 + ln];
#pragma unroll
            for (int r = 0; r < 4; r++) acc5[r] += s1s[w][r][i2] * wv;
        }
#pragma unroll
        for (int r = 0; r < 4; r++) {
            const float h2 = silu_f(acc5[r]);
            float q0 = h2 * wq0, q1 = h2 * wq1;
            RED64(q0); RED64(q1);
            if (ln == 0) {
                const int nl = r * 2 + w;
                const int n = node0 + nl;
                const float gate = q1 + sc2b2[1];
                const float l0o  = q0 + sc2b2[0];
                l0v[n] = l0o;
                l1v[(size_t)n * 3 + 0] = gate * g0[r];
                l1v[(size_t)n * 3 + 1] = gate * g1[r];
                l1v[(size_t)n * 3 + 2] = gate * g2[r];
                gateS[nl] = gate;
                l0S[nl]   = l0o;
            }
        }
    }
    __syncthreads();

    // P-emit tail: layout [node][h<30][8] = {pv0,pv1,pv2,pr0,pr1,pr2,ps,0}
    {
        const int nl = t >> 4;          // 0..7
        const int q  = t & 15;          // 0..15
        const int n  = node0 + nl;
        const float lj0 = gateS[nl] * pwp[nl][1];
        const float lj1 = gateS[nl] * pwp[nl][3];
        const float lj2 = gateS[nl] * pwp[nl][5];
        const float l0j = l0S[nl];
        const float pj0 = pos[n * 3 + 0], pj1 = pos[n * 3 + 1], pj2 = pos[n * 3 + 2];
        float* Pj = P + (size_t)n * PSTR;
        for (int h = q; h < 30; h += 16) {
            float o[8];
#pragma unroll
            for (int a = 0; a < 3; a++) {
                o[a]     = lj0 * vvW1[(3 * a + 0) * 30 + h]
                         + lj1 * vvW1[(3 * a + 1) * 30 + h]
                         + lj2 * vvW1[(3 * a + 2) * 30 + h];
                o[3 + a] = pj0 * vrW1[(3 * a + 0) * 30 + h]
                         + pj1 * vrW1[(3 * a + 1) * 30 + h]
                         + pj2 * vrW1[(3 * a + 2) * 30 + h];
            }
            o[6] = sb1[h] + l0j * sW1[30 + h];
            o[7] = 0.0f;
            *(float4*)&Pj[h * 8 + 0] = *(float4*)&o[0];
            *(float4*)&Pj[h * 8 + 4] = *(float4*)&o[4];
        }
    }
}

// ---------- pair kernel v7: explicit v_pk_fma_f32, weights in SGPR pairs ----
// Grid (A/4, B), 192 threads: g = t>=96, j = t%96; thread owns i = ni0, ni0+1.
// Packing axis = OUTPUT channels (l-pairs / h-pairs) so weight pairs are
// contiguous + wave-uniform (SGPR operand); silu/t9 operands broadcast via
// op_sel -> no splat movs. ~24 pk-FMA + 6 silu per h vs ~190 scalar ops before.
__global__ __launch_bounds__(192)
void pair_k(const float* __restrict__ l0v, const float* __restrict__ l1v,
            const float* __restrict__ P,
            const float* __restrict__ vvb1, const float* __restrict__ vrb1,
            const float* __restrict__ sW1,
            const float* __restrict__ vvW2, const float* __restrict__ vrW2,
            const float* __restrict__ sW2,
            const float* __restrict__ vvb2, const float* __restrict__ vrb2,
            const float* __restrict__ sb2,
            const float* __restrict__ hW1,  const float* __restrict__ hb1,
            const float* __restrict__ hW2,  const float* __restrict__ hb2,
            float* __restrict__ out) {
    const int t = threadIdx.x;
    const int b = blockIdx.y;
    const int g = (t >= 96) ? 1 : 0;
    const int j = t - g * 96;
    const int i0 = blockIdx.x * 4 + g * 2;
    const int ni0 = b * A_ATOMS + i0;       // thread: i = ni0, ni0+1
    const int nj  = b * A_ATOMS + j;
    const float* Pj = P + (size_t)nj * PSTR;

    const float li0x = l1v[ni0 * 3 + 0], li0y = l1v[ni0 * 3 + 1], li0z = l1v[ni0 * 3 + 2];
    const float li1x = l1v[(ni0 + 1) * 3 + 0], li1y = l1v[(ni0 + 1) * 3 + 1],
                li1z = l1v[(ni0 + 1) * 3 + 2];
    const float s00 = l0v[ni0], s01 = l0v[ni0 + 1];

    // t9 accumulators packed along l: tA?[lp] = (t9[2lp], t9[2lp+1]); t8 = t9[8]
    v2f tA0[4], tA1[4];
    float t80, t81;
#pragma unroll
    for (int lp = 0; lp < 4; lp++) {
        v2f tb = { vvb2[2 * lp] + vrb2[2 * lp] + sb2[2 * lp],
                   vvb2[2 * lp + 1] + vrb2[2 * lp + 1] + sb2[2 * lp + 1] };
        tA0[lp] = tb; tA1[lp] = tb;
    }
    t80 = t81 = vvb2[8] + vrb2[8] + sb2[8];

#pragma unroll 2
    for (int h = 0; h < 30; h++) {
        const float4 w0 = *(const float4*)&Pj[h * 8 + 0];
        const float4 w1 = *(const float4*)&Pj[h * 8 + 4];
        const float bv = vvb1[h], br = vrb1[h], sw = sW1[h];
        const u64 wv0 = ldw2(vvW2 + h * 9 + 0), wv1 = ldw2(vvW2 + h * 9 + 2);
        const u64 wv2 = ldw2(vvW2 + h * 9 + 4), wv3 = ldw2(vvW2 + h * 9 + 6);
        const u64 wr0 = ldw2(vrW2 + h * 9 + 0), wr1 = ldw2(vrW2 + h * 9 + 2);
        const u64 wr2 = ldw2(vrW2 + h * 9 + 4), wr3 = ldw2(vrW2 + h * 9 + 6);
        const u64 ws0 = ldw2(sW2 + h * 9 + 0),  ws1 = ldw2(sW2 + h * 9 + 2);
        const u64 ws2 = ldw2(sW2 + h * 9 + 4),  ws3 = ldw2(sW2 + h * 9 + 6);
        const float wv8 = vvW2[h * 9 + 8], wr8 = vrW2[h * 9 + 8], ws8 = sW2[h * 9 + 8];

        const float av0 = silu_f(w0.x * li0x + w0.y * li0y + w0.z * li0z + bv);
        const float ar0 = silu_f(w0.w * li0x + w1.x * li0y + w1.y * li0z + br);
        const float as0 = silu_f(w1.z + s00 * sw);
        const float av1 = silu_f(w0.x * li1x + w0.y * li1y + w0.z * li1z + bv);
        const float ar1 = silu_f(w0.w * li1x + w1.x * li1y + w1.y * li1z + br);
        const float as1 = silu_f(w1.z + s01 * sw);
        const v2f avp = { av0, av1 }, arp = { ar0, ar1 }, asp = { as0, as1 };

        pkfma_lo(tA0[0], avp, wv0); pkfma_lo(tA0[0], arp, wr0); pkfma_lo(tA0[0], asp, ws0);
        pkfma_lo(tA0[1], avp, wv1); pkfma_lo(tA0[1], arp, wr1); pkfma_lo(tA0[1], asp, ws1);
        pkfma_lo(tA0[2], avp, wv2); pkfma_lo(tA0[2], arp, wr2); pkfma_lo(tA0[2], asp, ws2);
        pkfma_lo(tA0[3], avp, wv3); pkfma_lo(tA0[3], arp, wr3); pkfma_lo(tA0[3], asp, ws3);
        pkfma_hi(tA1[0], avp, wv0); pkfma_hi(tA1[0], arp, wr0); pkfma_hi(tA1[0], asp, ws0);
        pkfma_hi(tA1[1], avp, wv1); pkfma_hi(tA1[1], arp, wr1); pkfma_hi(tA1[1], asp, ws1);
        pkfma_hi(tA1[2], avp, wv2); pkfma_hi(tA1[2], arp, wr2); pkfma_hi(tA1[2], asp, ws2);
        pkfma_hi(tA1[3], avp, wv3); pkfma_hi(tA1[3], arp, wr3); pkfma_hi(tA1[3], asp, ws3);
        t80 += av0 * wv8 + ar0 * wr8 + as0 * ws8;
        t81 += av1 * wv8 + ar1 * wr8 + as1 * ws8;
    }

    // ---- h-MLP 9->30->9, h processed in pairs; o packed along l -------------
    v2f oA0[4], oA1[4];
    float o80, o81;
#pragma unroll
    for (int lp = 0; lp < 4; lp++) {
        v2f ob = { hb2[2 * lp], hb2[2 * lp + 1] };
        oA0[lp] = ob; oA1[lp] = ob;
    }
    o80 = o81 = hb2[8];

    const v2f t8p0 = { t80, t80 }, t8p1 = { t81, t81 };

#pragma unroll 3
    for (int hp = 0; hp < 15; hp++) {
        const int h0 = 2 * hp, h1 = 2 * hp + 1;
        v2f a0 = { hb1[h0], hb1[h1] };
        v2f a1 = a0;
#pragma unroll
        for (int lp = 0; lp < 4; lp++) {
            const u64 wm0 = ldw2(hW1 + (2 * lp) * 30 + h0);
            const u64 wm1 = ldw2(hW1 + (2 * lp + 1) * 30 + h0);
            pkfma_lo(a0, tA0[lp], wm0); pkfma_hi(a0, tA0[lp], wm1);
            pkfma_lo(a1, tA1[lp], wm0); pkfma_hi(a1, tA1[lp], wm1);
        }
        const u64 w8 = ldw2(hW1 + 8 * 30 + h0);
        pkfma(a0, t8p0, w8);
        pkfma(a1, t8p1, w8);

        const float sx0 = silu_f(a0.x), sy0 = silu_f(a0.y);
        const float sx1 = silu_f(a1.x), sy1 = silu_f(a1.y);
        const v2f sp0 = { sx0, sy0 }, sp1 = { sx1, sy1 };

#pragma unroll
        for (int lp = 0; lp < 4; lp++) {
            const u64 u0 = ldw2(hW2 + h0 * 9 + 2 * lp);
            const u64 u1 = ldw2(hW2 + h1 * 9 + 2 * lp);
            pkfma_lo(oA0[lp], sp0, u0); pkfma_hi(oA0[lp], sp0, u1);
            pkfma_lo(oA1[lp], sp1, u0); pkfma_hi(oA1[lp], sp1, u1);
        }
        const float z0 = hW2[h0 * 9 + 8], z1 = hW2[h1 * 9 + 8];
        o80 += sx0 * z0 + sy0 * z1;
        o81 += sx1 * z0 + sy1 * z1;
    }

    // out[((b*A+i)*3+k)*288 + j*3 + l]
    float q0[9] = { oA0[0].x, oA0[0].y, oA0[1].x, oA0[1].y,
                    oA0[2].x, oA0[2].y, oA0[3].x, oA0[3].y, o80 };
    float q1[9] = { oA1[0].x, oA1[0].y, oA1[1].x, oA1[1].y,
                    oA1[2].x, oA1[2].y, oA1[3].x, oA1[3].y, o81 };
#pragma unroll
    for (int k = 0; k < 3; k++) {
        const size_t base0 = ((size_t)ni0 * 3 + k) * 288 + (size_t)j * 3;
        out[base0 + 0] = q0[3 * k + 0];
        out[base0 + 1] = q0[3 * k + 1];
        out[base0 + 2] = q0[3 * k + 2];
        const size_t base1 = base0 + 3 * 288;
        out[base1 + 0] = q1[3 * k + 0];
        out[base1 + 1] = q1[3 * k + 1];
        out[base1 + 2] = q1[3 * k + 2];
    }
}

extern "C" void kernel_launch(void* const* d_in, const int* in_sizes, int n_in,
                              void* d_out, int out_size, void* d_ws, size_t ws_size,
                              hipStream_t stream) {
    const float* pos   = (const float*)d_in[0];
    const float* srep  = (const float*)d_in[1];
    const float* vrep  = (const float*)d_in[2];
    const float* mixW1 = (const float*)d_in[3];
    const float* sc1W1 = (const float*)d_in[4];
    const float* sc1b1 = (const float*)d_in[5];
    const float* sc1W2 = (const float*)d_in[6];
    const float* sc1b2 = (const float*)d_in[7];
    const float* mixW2 = (const float*)d_in[8];
    const float* sc2W1 = (const float*)d_in[9];
    const float* sc2b1 = (const float*)d_in[10];
    const float* sc2W2 = (const float*)d_in[11];
    const float* sc2b2 = (const float*)d_in[12];
    const float* vvW1  = (const float*)d_in[13];
    const float* vvb1  = (const float*)d_in[14];
    const float* vvW2  = (const float*)d_in[15];
    const float* vvb2  = (const float*)d_in[16];
    const float* vrW1  = (const float*)d_in[17];
    const float* vrb1  = (const float*)d_in[18];
    const float* vrW2  = (const float*)d_in[19];
    const float* vrb2  = (const float*)d_in[20];
    const float* sW1   = (const float*)d_in[21];
    const float* sb1   = (const float*)d_in[22];
    const float* sW2   = (const float*)d_in[23];
    const float* sb2   = (const float*)d_in[24];
    const float* hW1   = (const float*)d_in[25];
    const float* hb1   = (const float*)d_in[26];
    const float* hW2   = (const float*)d_in[27];
    const float* hb2   = (const float*)d_in[28];

    float* ws  = (float*)d_ws;
    float* P   = ws;                               // PSTR*NNODES floats
    float* l0v = P + (size_t)PSTR * NNODES;        // 12,288
    float* l1v = l0v + NNODES;                     // 36,864
    float* outf = (float*)d_out;

    // 1. fused node stage -> l0, l1, P
    node_k<<<NNODES / NB, 128, 0, stream>>>(
        vrep, mixW1, srep,
        sc1W1, sc1b1, sc1W2, sc1b2,
        mixW2, sc2W1, sc2b1, sc2W2, sc2b2,
        pos, vvW1, vrW1, sW1, sb1,
        l0v, l1v, P);

    // 2. pair stage (2 i per thread, packed v_pk_fma_f32)
    pair_k<<<dim3(A_ATOMS / 4, BATCH), 192, 0, stream>>>(
        l0v, l1v, P,
        vvb1, vrb1, sW1,
        vvW2, vrW2, sW2,
        vvb2, vrb2, sb2,
        hW1, hb1, hW2, hb2,
        outf);
}